// Round 4
// baseline (674.862 us; speedup 1.0000x reference)
//
#include <hip/hip_runtime.h>

// Problem constants (from reference): IN_DIM=128, H=8, D=16, HD=128.
#define HD 128

__device__ inline void fma4(float4& a, float s, const float4& w) {
    a.x = fmaf(s, w.x, a.x);
    a.y = fmaf(s, w.y, a.y);
    a.z = fmaf(s, w.z, a.z);
    a.w = fmaf(s, w.w, a.w);
}

// ---------------- K1: fused QKV projection ----------------
// Block: 256 threads, 64 rows of h staged in LDS, computes Q,K,V rows.
// Thread (cg,rg): cols c0..c0+3 (cg=tid&31), rows rb..rb+7 (rg=tid>>5).
__global__ __launch_bounds__(256) void qkv_kernel(
    const float* __restrict__ h,
    const float* __restrict__ WQ, const float* __restrict__ bQ,
    const float* __restrict__ WK, const float* __restrict__ bK,
    const float* __restrict__ WV, const float* __restrict__ bV,
    float* __restrict__ Q, float* __restrict__ K, float* __restrict__ V,
    int N)
{
    __shared__ float hs[64 * 128];
    const int tid = threadIdx.x;
    const int r0 = blockIdx.x * 64;

    // Stage h tile [64][128] (2048 float4, 8 per thread, coalesced).
    #pragma unroll
    for (int j = 0; j < 8; ++j) {
        int id = j * 256 + tid;      // float4 index
        int row = id >> 5;           // 32 float4 per row
        int c4 = (id & 31) << 2;
        float4 v = make_float4(0.f, 0.f, 0.f, 0.f);
        if (r0 + row < N)
            v = *(const float4*)(h + (size_t)(r0 + row) * 128 + c4);
        *(float4*)(hs + row * 128 + c4) = v;
    }
    __syncthreads();

    const int cg = tid & 31, rg = tid >> 5;
    const int c0 = cg * 4, rb = rg * 8;

    const float* Ws[3] = {WQ, WK, WV};
    const float* bs[3] = {bQ, bK, bV};
    float* Os[3] = {Q, K, V};

    for (int m = 0; m < 3; ++m) {
        const float* __restrict__ W = Ws[m];
        float4 acc[8];
        #pragma unroll
        for (int i = 0; i < 8; ++i) acc[i] = make_float4(0.f, 0.f, 0.f, 0.f);

        for (int k = 0; k < 128; k += 4) {
            float4 w0 = *(const float4*)(W + (size_t)(k + 0) * HD + c0);
            float4 w1 = *(const float4*)(W + (size_t)(k + 1) * HD + c0);
            float4 w2 = *(const float4*)(W + (size_t)(k + 2) * HD + c0);
            float4 w3 = *(const float4*)(W + (size_t)(k + 3) * HD + c0);
            #pragma unroll
            for (int i = 0; i < 8; ++i) {
                float4 hv = *(const float4*)(hs + (rb + i) * 128 + k);
                fma4(acc[i], hv.x, w0);
                fma4(acc[i], hv.y, w1);
                fma4(acc[i], hv.z, w2);
                fma4(acc[i], hv.w, w3);
            }
        }
        float4 bv = *(const float4*)(bs[m] + c0);
        #pragma unroll
        for (int i = 0; i < 8; ++i) {
            acc[i].x += bv.x; acc[i].y += bv.y; acc[i].z += bv.z; acc[i].w += bv.w;
            int row = r0 + rb + i;
            if (row < N)
                *(float4*)(Os[m] + (size_t)row * HD + c0) = acc[i];
        }
    }
}

// ---------------- K2: histogram of dst ----------------
__global__ __launch_bounds__(256) void hist_kernel(
    const int* __restrict__ dst, int* __restrict__ C, int E)
{
    int e = blockIdx.x * 256 + threadIdx.x;
    if (e < E) atomicAdd(&C[dst[e]], 1);
}

// ---------------- K3a: per-tile (1024 counts) sums ----------------
__global__ __launch_bounds__(256) void scan_a(
    const int* __restrict__ C, int* __restrict__ tileSum, int N)
{
    __shared__ int red[256];
    const int t = blockIdx.x, tid = threadIdx.x;
    int base = t * 1024 + tid * 4;
    int s = 0;
    #pragma unroll
    for (int i = 0; i < 4; ++i)
        if (base + i < N) s += C[base + i];
    red[tid] = s;
    __syncthreads();
    for (int off = 128; off > 0; off >>= 1) {
        if (tid < off) red[tid] += red[tid + off];
        __syncthreads();
    }
    if (tid == 0) tileSum[t] = red[0];
}

// ---------------- K3b: exclusive scan of tile sums (single block) ----------------
__global__ __launch_bounds__(1024) void scan_b(
    const int* __restrict__ tileSum, int* __restrict__ tileOff, int numTiles)
{
    __shared__ int buf[1024];
    const int t = threadIdx.x;
    int v = (t < numTiles) ? tileSum[t] : 0;
    buf[t] = v;
    __syncthreads();
    for (int off = 1; off < 1024; off <<= 1) {
        int x = (t >= off) ? buf[t - off] : 0;
        __syncthreads();
        buf[t] += x;
        __syncthreads();
    }
    if (t < numTiles) tileOff[t] = buf[t] - v;  // exclusive
}

// ---------------- K3c: per-tile exclusive scan -> offsets + cursor ----------------
__global__ __launch_bounds__(256) void scan_c(
    const int* __restrict__ C, const int* __restrict__ tileOff,
    int* __restrict__ O, int* __restrict__ U, int N, int E)
{
    __shared__ int buf[256];
    const int t = blockIdx.x, tid = threadIdx.x;
    int base = t * 1024 + tid * 4;
    int c[4];
    #pragma unroll
    for (int i = 0; i < 4; ++i)
        c[i] = (base + i < N) ? C[base + i] : 0;
    int tsum = c[0] + c[1] + c[2] + c[3];
    buf[tid] = tsum;
    __syncthreads();
    for (int off = 1; off < 256; off <<= 1) {
        int x = (tid >= off) ? buf[tid - off] : 0;
        __syncthreads();
        buf[tid] += x;
        __syncthreads();
    }
    int run = buf[tid] - tsum + tileOff[t];  // exclusive prefix
    #pragma unroll
    for (int i = 0; i < 4; ++i) {
        if (base + i < N) { O[base + i] = run; U[base + i] = run; }
        run += c[i];
    }
    if (t == 0 && tid == 0) O[N] = E;
}

// ---------------- K4: scatter src ids into CSR order ----------------
__global__ __launch_bounds__(256) void scatter_kernel(
    const int* __restrict__ src, const int* __restrict__ dst,
    int* __restrict__ U, int* __restrict__ srclist, int E)
{
    int e = blockIdx.x * 256 + threadIdx.x;
    if (e < E) {
        int p = atomicAdd(&U[dst[e]], 1);
        srclist[p] = src[e];
    }
}

// ---------------- K5: per-node aggregation (1 wave = 1 node) ----------------
// Half-wave-per-edge layout: lane l owns elements 4*(l&31)..+3 (float4).
// Lanes 0-31 process even edges of a pair-step, lanes 32-63 the odd edges.
// Head = 16 elems = 4 lanes -> dot reduce is 2 shfl_xor, shared by both edges.
// Main loop: 4 pair-steps unrolled = 8 edges / 16 gathers in flight.
__global__ __launch_bounds__(256) void agg_kernel(
    const float* __restrict__ Q, const float* __restrict__ K,
    const float* __restrict__ V, const int* __restrict__ O,
    const int* __restrict__ srclist, float* __restrict__ out, int N)
{
    const int l = threadIdx.x & 63;
    const int n = blockIdx.x * 4 + (threadIdx.x >> 6);
    if (n >= N) return;

    const int half = l >> 5;          // 0: even edge, 1: odd edge
    const int c4 = (l & 31) * 4;      // element offset within the row

    float4 q = *(const float4*)(Q + (size_t)n * HD + c4);
    float4 acc = make_float4(0.f, 0.f, 0.f, 0.f);
    float z = 0.f;
    const int start = O[n], end = O[n + 1];

    for (int base = start; base < end; base += 64) {
        int sv = 0;
        if (base + l < end) sv = srclist[base + l];
        const int cnt = min(64, end - base);
        int j = 0;
        for (; j + 8 <= cnt; j += 8) {          // 8 edges per iteration
            float4 kv[4], vv[4];
            #pragma unroll
            for (int u = 0; u < 4; ++u) {
                int s = __shfl(sv, j + 2 * u + half);
                kv[u] = *(const float4*)(K + (size_t)s * HD + c4);
                vv[u] = *(const float4*)(V + (size_t)s * HD + c4);
            }
            #pragma unroll
            for (int u = 0; u < 4; ++u) {
                float p = fmaf(kv[u].x, q.x,
                          fmaf(kv[u].y, q.y,
                          fmaf(kv[u].z, q.z, kv[u].w * q.w)));
                p += __shfl_xor(p, 1);
                p += __shfl_xor(p, 2);
                float sc = __expf(fminf(5.f, fmaxf(-5.f, p * 0.25f)));
                z += sc;
                fma4(acc, sc, vv[u]);
            }
        }
        for (; j < cnt; j += 2) {               // pair tail (maybe odd edge)
            int e = j + half;
            bool valid = e < cnt;
            int s = __shfl(sv, valid ? e : j);
            float4 kv = *(const float4*)(K + (size_t)s * HD + c4);
            float4 vv = *(const float4*)(V + (size_t)s * HD + c4);
            float p = fmaf(kv.x, q.x,
                      fmaf(kv.y, q.y,
                      fmaf(kv.z, q.z, kv.w * q.w)));
            p += __shfl_xor(p, 1);
            p += __shfl_xor(p, 2);
            float sc = __expf(fminf(5.f, fmaxf(-5.f, p * 0.25f)));
            if (!valid) sc = 0.f;
            z += sc;
            fma4(acc, sc, vv);
        }
    }

    // Combine the two half-wave partial sums (same elements, disjoint edges).
    acc.x += __shfl_xor(acc.x, 32);
    acc.y += __shfl_xor(acc.y, 32);
    acc.z += __shfl_xor(acc.z, 32);
    acc.w += __shfl_xor(acc.w, 32);
    z     += __shfl_xor(z, 32);

    if (half == 0) {
        float4 res;
        res.x = acc.x / z;
        res.y = acc.y / z;
        res.z = acc.z / z;
        res.w = acc.w / z;
        *(float4*)(out + (size_t)n * HD + c4) = res;
    }
}

extern "C" void kernel_launch(void* const* d_in, const int* in_sizes, int n_in,
                              void* d_out, int out_size, void* d_ws, size_t ws_size,
                              hipStream_t stream)
{
    const float* h  = (const float*)d_in[0];
    const float* WQ = (const float*)d_in[1];
    const float* bQ = (const float*)d_in[2];
    const float* WK = (const float*)d_in[3];
    const float* bK = (const float*)d_in[4];
    const float* WV = (const float*)d_in[5];
    const float* bV = (const float*)d_in[6];
    const int* src  = (const int*)d_in[7];
    const int* dst  = (const int*)d_in[8];
    float* out = (float*)d_out;

    const int N = in_sizes[0] / 128;
    const int E = in_sizes[7];
    const int numTiles = (N + 1023) / 1024;

    // Carve workspace (256B aligned chunks).
    char* w = (char*)d_ws;
    auto alloc = [&](size_t bytes) {
        char* p = w;
        w += (bytes + 255) & ~(size_t)255;
        return p;
    };
    float* Q = (float*)alloc((size_t)N * HD * 4);
    float* K = (float*)alloc((size_t)N * HD * 4);
    float* V = (float*)alloc((size_t)N * HD * 4);
    int* O        = (int*)alloc((size_t)(N + 1) * 4);
    int* U        = (int*)alloc((size_t)N * 4);
    int* C        = (int*)alloc((size_t)N * 4);
    int* tileSum  = (int*)alloc((size_t)numTiles * 4);
    int* tileOff  = (int*)alloc((size_t)numTiles * 4);
    int* srclist  = (int*)alloc((size_t)E * 4);

    hipMemsetAsync(C, 0, (size_t)N * 4, stream);

    qkv_kernel<<<(N + 63) / 64, 256, 0, stream>>>(h, WQ, bQ, WK, bK, WV, bV, Q, K, V, N);
    hist_kernel<<<(E + 255) / 256, 256, 0, stream>>>(dst, C, E);
    scan_a<<<numTiles, 256, 0, stream>>>(C, tileSum, N);
    scan_b<<<1, 1024, 0, stream>>>(tileSum, tileOff, numTiles);
    scan_c<<<numTiles, 256, 0, stream>>>(C, tileOff, O, U, N, E);
    scatter_kernel<<<(E + 255) / 256, 256, 0, stream>>>(src, dst, U, srclist, E);
    agg_kernel<<<(N + 3) / 4, 256, 0, stream>>>(Q, K, V, O, srclist, out, N);
}

// Round 6
// 601.063 us; speedup vs baseline: 1.1228x; 1.1228x over previous
//
#include <hip/hip_runtime.h>

// Problem constants (from reference): IN_DIM=128, H=8, D=16, HD=128.
#define HD 128

typedef float f4v __attribute__((ext_vector_type(4)));

__device__ inline void fma4(float4& a, float s, const float4& w) {
    a.x = fmaf(s, w.x, a.x);
    a.y = fmaf(s, w.y, a.y);
    a.z = fmaf(s, w.z, a.z);
    a.w = fmaf(s, w.w, a.w);
}

// ---------------- K1: fused QKV projection ----------------
// Writes Q to its own array; K and V interleaved per node into KV:
// KV[n*256 + 0..127] = K row, KV[n*256 + 128..255] = V row.
__global__ __launch_bounds__(256) void qkv_kernel(
    const float* __restrict__ h,
    const float* __restrict__ WQ, const float* __restrict__ bQ,
    const float* __restrict__ WK, const float* __restrict__ bK,
    const float* __restrict__ WV, const float* __restrict__ bV,
    float* __restrict__ Q, float* __restrict__ KV,
    int N)
{
    __shared__ float hs[64 * 128];
    const int tid = threadIdx.x;
    const int r0 = blockIdx.x * 64;

    // Stage h tile [64][128] (2048 float4, 8 per thread, coalesced, read-once).
    #pragma unroll
    for (int j = 0; j < 8; ++j) {
        int id = j * 256 + tid;      // float4 index
        int row = id >> 5;           // 32 float4 per row
        int c4 = (id & 31) << 2;
        f4v v = {0.f, 0.f, 0.f, 0.f};
        if (r0 + row < N)
            v = __builtin_nontemporal_load((const f4v*)(h + (size_t)(r0 + row) * 128 + c4));
        *(f4v*)(hs + row * 128 + c4) = v;
    }
    __syncthreads();

    const int cg = tid & 31, rg = tid >> 5;
    const int c0 = cg * 4, rb = rg * 8;

    const float* Ws[3] = {WQ, WK, WV};
    const float* bs[3] = {bQ, bK, bV};
    float* outBase[3] = {Q, KV, KV + 128};
    const size_t outStride[3] = {128, 256, 256};

    for (int m = 0; m < 3; ++m) {
        const float* __restrict__ W = Ws[m];
        float4 acc[8];
        #pragma unroll
        for (int i = 0; i < 8; ++i) acc[i] = make_float4(0.f, 0.f, 0.f, 0.f);

        for (int k = 0; k < 128; k += 4) {
            float4 w0 = *(const float4*)(W + (size_t)(k + 0) * HD + c0);
            float4 w1 = *(const float4*)(W + (size_t)(k + 1) * HD + c0);
            float4 w2 = *(const float4*)(W + (size_t)(k + 2) * HD + c0);
            float4 w3 = *(const float4*)(W + (size_t)(k + 3) * HD + c0);
            #pragma unroll
            for (int i = 0; i < 8; ++i) {
                float4 hv = *(const float4*)(hs + (rb + i) * 128 + k);
                fma4(acc[i], hv.x, w0);
                fma4(acc[i], hv.y, w1);
                fma4(acc[i], hv.z, w2);
                fma4(acc[i], hv.w, w3);
            }
        }
        float4 bv = *(const float4*)(bs[m] + c0);
        float* ob = outBase[m];
        const size_t st = outStride[m];
        #pragma unroll
        for (int i = 0; i < 8; ++i) {
            acc[i].x += bv.x; acc[i].y += bv.y; acc[i].z += bv.z; acc[i].w += bv.w;
            int row = r0 + rb + i;
            if (row < N)
                *(float4*)(ob + (size_t)row * st + c0) = acc[i];
        }
    }
}

// ---------------- K2: rank pass (single atomic pass) ----------------
// U must be zeroed. Afterwards U[n] = degree(n), rank[e] = stable slot.
__global__ __launch_bounds__(256) void rank_kernel(
    const int* __restrict__ dst, int* __restrict__ U,
    int* __restrict__ rank, int E)
{
    int e = blockIdx.x * 256 + threadIdx.x;
    if (e < E) {
        int r = atomicAdd(&U[dst[e]], 1);
        __builtin_nontemporal_store(r, &rank[e]);
    }
}

// ---------------- K3a: per-tile (1024 counts) sums ----------------
__global__ __launch_bounds__(256) void scan_a(
    const int* __restrict__ C, int* __restrict__ tileSum, int N)
{
    __shared__ int red[256];
    const int t = blockIdx.x, tid = threadIdx.x;
    int base = t * 1024 + tid * 4;
    int s = 0;
    #pragma unroll
    for (int i = 0; i < 4; ++i)
        if (base + i < N) s += C[base + i];
    red[tid] = s;
    __syncthreads();
    for (int off = 128; off > 0; off >>= 1) {
        if (tid < off) red[tid] += red[tid + off];
        __syncthreads();
    }
    if (tid == 0) tileSum[t] = red[0];
}

// ---------------- K3b: exclusive scan of tile sums (single block) ----------------
__global__ __launch_bounds__(1024) void scan_b(
    const int* __restrict__ tileSum, int* __restrict__ tileOff, int numTiles)
{
    __shared__ int buf[1024];
    const int t = threadIdx.x;
    int v = (t < numTiles) ? tileSum[t] : 0;
    buf[t] = v;
    __syncthreads();
    for (int off = 1; off < 1024; off <<= 1) {
        int x = (t >= off) ? buf[t - off] : 0;
        __syncthreads();
        buf[t] += x;
        __syncthreads();
    }
    if (t < numTiles) tileOff[t] = buf[t] - v;  // exclusive
}

// ---------------- K3c: per-tile exclusive scan -> row offsets O ----------------
__global__ __launch_bounds__(256) void scan_c(
    const int* __restrict__ C, const int* __restrict__ tileOff,
    int* __restrict__ O, int N, int E)
{
    __shared__ int buf[256];
    const int t = blockIdx.x, tid = threadIdx.x;
    int base = t * 1024 + tid * 4;
    int c[4];
    #pragma unroll
    for (int i = 0; i < 4; ++i)
        c[i] = (base + i < N) ? C[base + i] : 0;
    int tsum = c[0] + c[1] + c[2] + c[3];
    buf[tid] = tsum;
    __syncthreads();
    for (int off = 1; off < 256; off <<= 1) {
        int x = (tid >= off) ? buf[tid - off] : 0;
        __syncthreads();
        buf[tid] += x;
        __syncthreads();
    }
    int run = buf[tid] - tsum + tileOff[t];  // exclusive prefix
    #pragma unroll
    for (int i = 0; i < 4; ++i) {
        if (base + i < N) O[base + i] = run;
        run += c[i];
    }
    if (t == 0 && tid == 0) O[N] = E;
}

// ---------------- K4: deterministic scatter (no atomics) ----------------
__global__ __launch_bounds__(256) void scatter_kernel(
    const int* __restrict__ src, const int* __restrict__ dst,
    const int* __restrict__ O, const int* __restrict__ rank,
    int* __restrict__ srclist, int E)
{
    int e = blockIdx.x * 256 + threadIdx.x;
    if (e < E) {
        __builtin_nontemporal_store(src[e], &srclist[O[dst[e]] + rank[e]]);
    }
}

// ---------------- K5: per-node aggregation (1 wave = 1 node) ----------------
// Half-wave-per-edge layout: lane l owns elements 4*(l&31)..+3 (float4).
// Lanes 0-31 process even edges of a pair-step, lanes 32-63 the odd edges.
// KV packed: node row = 256 floats (K then V) -> one contiguous 1KB region/edge.
// Streaming arrays (Q, O, srclist, out) use nontemporal hints to keep L2 for KV.
__global__ __launch_bounds__(256) void agg_kernel(
    const float* __restrict__ Q, const float* __restrict__ KV,
    const int* __restrict__ O, const int* __restrict__ srclist,
    float* __restrict__ out, int N)
{
    const int l = threadIdx.x & 63;
    const int n = blockIdx.x * 4 + (threadIdx.x >> 6);
    if (n >= N) return;

    const int half = l >> 5;          // 0: even edge, 1: odd edge
    const int c4 = (l & 31) * 4;      // element offset within the row

    f4v q = __builtin_nontemporal_load((const f4v*)(Q + (size_t)n * HD + c4));
    f4v acc = {0.f, 0.f, 0.f, 0.f};
    float z = 0.f;
    const int start = __builtin_nontemporal_load(&O[n]);
    const int end   = __builtin_nontemporal_load(&O[n + 1]);

    for (int base = start; base < end; base += 64) {
        int sv = 0;
        if (base + l < end) sv = __builtin_nontemporal_load(&srclist[base + l]);
        const int cnt = min(64, end - base);
        int j = 0;
        for (; j + 8 <= cnt; j += 8) {          // 8 edges per iteration
            f4v kv[4], vv[4];
            #pragma unroll
            for (int u = 0; u < 4; ++u) {
                int s = __shfl(sv, j + 2 * u + half);
                const float* row = KV + (size_t)s * 256;
                kv[u] = *(const f4v*)(row + c4);
                vv[u] = *(const f4v*)(row + 128 + c4);
            }
            #pragma unroll
            for (int u = 0; u < 4; ++u) {
                float p = fmaf(kv[u][0], q[0],
                          fmaf(kv[u][1], q[1],
                          fmaf(kv[u][2], q[2], kv[u][3] * q[3])));
                p += __shfl_xor(p, 1);
                p += __shfl_xor(p, 2);
                float sc = __expf(fminf(5.f, fmaxf(-5.f, p * 0.25f)));
                z += sc;
                acc += sc * vv[u];
            }
        }
        for (; j < cnt; j += 2) {               // pair tail (maybe odd edge)
            int e = j + half;
            bool valid = e < cnt;
            int s = __shfl(sv, valid ? e : j);
            const float* row = KV + (size_t)s * 256;
            f4v kv = *(const f4v*)(row + c4);
            f4v vv = *(const f4v*)(row + 128 + c4);
            float p = fmaf(kv[0], q[0],
                      fmaf(kv[1], q[1],
                      fmaf(kv[2], q[2], kv[3] * q[3])));
            p += __shfl_xor(p, 1);
            p += __shfl_xor(p, 2);
            float sc = __expf(fminf(5.f, fmaxf(-5.f, p * 0.25f)));
            if (!valid) sc = 0.f;
            z += sc;
            acc += sc * vv;
        }
    }

    // Combine the two half-wave partial sums (same elements, disjoint edges).
    acc[0] += __shfl_xor(acc[0], 32);
    acc[1] += __shfl_xor(acc[1], 32);
    acc[2] += __shfl_xor(acc[2], 32);
    acc[3] += __shfl_xor(acc[3], 32);
    z      += __shfl_xor(z, 32);

    if (half == 0) {
        f4v res = acc / z;
        __builtin_nontemporal_store(res, (f4v*)(out + (size_t)n * HD + c4));
    }
}

extern "C" void kernel_launch(void* const* d_in, const int* in_sizes, int n_in,
                              void* d_out, int out_size, void* d_ws, size_t ws_size,
                              hipStream_t stream)
{
    const float* h  = (const float*)d_in[0];
    const float* WQ = (const float*)d_in[1];
    const float* bQ = (const float*)d_in[2];
    const float* WK = (const float*)d_in[3];
    const float* bK = (const float*)d_in[4];
    const float* WV = (const float*)d_in[5];
    const float* bV = (const float*)d_in[6];
    const int* src  = (const int*)d_in[7];
    const int* dst  = (const int*)d_in[8];
    float* out = (float*)d_out;

    const int N = in_sizes[0] / 128;
    const int E = in_sizes[7];
    const int numTiles = (N + 1023) / 1024;

    // Carve workspace (256B aligned chunks).
    char* w = (char*)d_ws;
    auto alloc = [&](size_t bytes) {
        char* p = w;
        w += (bytes + 255) & ~(size_t)255;
        return p;
    };
    float* Q  = (float*)alloc((size_t)N * HD * 4);
    float* KV = (float*)alloc((size_t)N * 256 * 4);
    int* O        = (int*)alloc((size_t)(N + 1) * 4);
    int* U        = (int*)alloc((size_t)N * 4);
    int* rank     = (int*)alloc((size_t)E * 4);
    int* tileSum  = (int*)alloc((size_t)numTiles * 4);
    int* tileOff  = (int*)alloc((size_t)numTiles * 4);
    int* srclist  = (int*)alloc((size_t)E * 4);

    hipMemsetAsync(U, 0, (size_t)N * 4, stream);

    qkv_kernel<<<(N + 63) / 64, 256, 0, stream>>>(h, WQ, bQ, WK, bK, WV, bV, Q, KV, N);
    rank_kernel<<<(E + 255) / 256, 256, 0, stream>>>(dst, U, rank, E);
    scan_a<<<numTiles, 256, 0, stream>>>(U, tileSum, N);
    scan_b<<<1, 1024, 0, stream>>>(tileSum, tileOff, numTiles);
    scan_c<<<numTiles, 256, 0, stream>>>(U, tileOff, O, N, E);
    scatter_kernel<<<(E + 255) / 256, 256, 0, stream>>>(src, dst, O, rank, srclist, E);
    agg_kernel<<<(N + 3) / 4, 256, 0, stream>>>(Q, KV, O, srclist, out, N);
}

// Round 7
// 523.581 us; speedup vs baseline: 1.2889x; 1.1480x over previous
//
#include <hip/hip_runtime.h>

// Problem constants (from reference): IN_DIM=128, H=8, D=16, HD=128.
#define HD 128

typedef float f4v __attribute__((ext_vector_type(4)));
typedef float f32x4 __attribute__((ext_vector_type(4)));
typedef short short8 __attribute__((ext_vector_type(8)));   // 8 bf16 = 4 VGPRs

// Round-to-nearest-even fp32 -> bf16 split: f ~= hi + lo (each bf16).
__device__ inline void bf16split(float f, unsigned short& hi, unsigned short& lo) {
    unsigned u = __builtin_bit_cast(unsigned, f);
    unsigned short h = (unsigned short)((u + 0x7FFFu + ((u >> 16) & 1u)) >> 16);
    float fh = __builtin_bit_cast(float, (unsigned)h << 16);
    float r = f - fh;                       // exact
    unsigned v = __builtin_bit_cast(unsigned, r);
    unsigned short l = (unsigned short)((v + 0x7FFFu + ((v >> 16) & 1u)) >> 16);
    hi = h; lo = l;
}

// ---------------- K0: weight prep ----------------
// Splits W_cat[128][384] (Q|K|V cols) into bf16 hi/lo in MFMA-fragment-ready
// layout: block (kt,nf) -> 512 entries, entry idx = l*8+e holds
// W[kt*32 + 8*(l>>4) + e][nf*16 + (l&15)].  Also builds bcat[384].
__global__ __launch_bounds__(256) void prep_kernel(
    const float* __restrict__ WQ, const float* __restrict__ WK,
    const float* __restrict__ WV,
    const float* __restrict__ bQ, const float* __restrict__ bK,
    const float* __restrict__ bV,
    unsigned short* __restrict__ Whi, unsigned short* __restrict__ Wlo,
    float* __restrict__ bcat)
{
    const int blk = blockIdx.x, tid = threadIdx.x;
    if (blk == 96) {
        for (int j = tid; j < 384; j += 256) {
            const float* b = (j < 128) ? bQ : (j < 256) ? bK : bV;
            bcat[j] = b[j & 127];
        }
        return;
    }
    const int kt = blk / 24, nf = blk % 24;
    #pragma unroll
    for (int t = 0; t < 2; ++t) {
        int idx = t * 256 + tid;           // 0..511
        int l = idx >> 3, e = idx & 7;
        int k = kt * 32 + ((l >> 4) << 3) + e;
        int j = nf * 16 + (l & 15);
        const float* W = (j < 128) ? WQ : (j < 256) ? WK : WV;
        float f = W[(size_t)k * 128 + (j & 127)];
        unsigned short hi, lo;
        bf16split(f, hi, lo);
        Whi[(size_t)blk * 512 + idx] = hi;
        Wlo[(size_t)blk * 512 + idx] = lo;
    }
}

// ---------------- K1: QKV projection via bf16x3 split MFMA ----------------
// Block: 512 threads (8 waves), 64 rows. Wave w computes rows 0..63 x cols
// [w*48, w*48+48). fp32 ~= hi*hi + hi*lo + lo*hi (lo*lo ~ 2^-17, dropped).
// Q -> [N,128]; K,V interleaved into KV rows of 256 (K at +0, V at +128).
__global__ __launch_bounds__(512, 2) void qkv_kernel(
    const float* __restrict__ h,
    const unsigned short* __restrict__ Whi, const unsigned short* __restrict__ Wlo,
    const float* __restrict__ bcat,
    float* __restrict__ Q, float* __restrict__ KV, int N)
{
    __shared__ unsigned short hsh[64 * 136];   // +8 pad: 2-way max bank conflict
    __shared__ unsigned short hsl[64 * 136];
    const int tid = threadIdx.x;
    const int r0 = blockIdx.x * 64;

    // Stage h tile [64][128] as bf16 hi/lo (coalesced float4 loads).
    #pragma unroll
    for (int jj = 0; jj < 4; ++jj) {
        int idf4 = jj * 512 + tid;         // float4 index in tile
        int row = idf4 >> 5;
        int c4 = (idf4 & 31) << 2;
        f4v v = {0.f, 0.f, 0.f, 0.f};
        if (r0 + row < N)
            v = __builtin_nontemporal_load((const f4v*)(h + (size_t)(r0 + row) * 128 + c4));
        ushort4 hv, lv;
        bf16split(v[0], hv.x, lv.x);
        bf16split(v[1], hv.y, lv.y);
        bf16split(v[2], hv.z, lv.z);
        bf16split(v[3], hv.w, lv.w);
        *(ushort4*)&hsh[row * 136 + c4] = hv;
        *(ushort4*)&hsl[row * 136 + c4] = lv;
    }
    __syncthreads();

    const int wid = tid >> 6, l = tid & 63;
    const int lrow = l & 15;
    const int lkOff = (l >> 4) << 3;       // 0,8,16,24

    f32x4 acc[4][3];
    #pragma unroll
    for (int mf = 0; mf < 4; ++mf)
        #pragma unroll
        for (int n3 = 0; n3 < 3; ++n3)
            acc[mf][n3] = (f32x4){0.f, 0.f, 0.f, 0.f};

    #pragma unroll
    for (int kt = 0; kt < 4; ++kt) {
        short8 ah[4], al[4];
        #pragma unroll
        for (int mf = 0; mf < 4; ++mf) {
            int off = (mf * 16 + lrow) * 136 + kt * 32 + lkOff;
            ah[mf] = *(const short8*)&hsh[off];
            al[mf] = *(const short8*)&hsl[off];
        }
        short8 bh[3], bl[3];
        #pragma unroll
        for (int n3 = 0; n3 < 3; ++n3) {
            size_t fb = ((size_t)(kt * 24 + wid * 3 + n3)) * 512 + l * 8;
            bh[n3] = *(const short8*)&Whi[fb];
            bl[n3] = *(const short8*)&Wlo[fb];
        }
        #pragma unroll
        for (int mf = 0; mf < 4; ++mf)
            #pragma unroll
            for (int n3 = 0; n3 < 3; ++n3) {
                acc[mf][n3] = __builtin_amdgcn_mfma_f32_16x16x32_bf16(ah[mf], bh[n3], acc[mf][n3], 0, 0, 0);
                acc[mf][n3] = __builtin_amdgcn_mfma_f32_16x16x32_bf16(ah[mf], bl[n3], acc[mf][n3], 0, 0, 0);
                acc[mf][n3] = __builtin_amdgcn_mfma_f32_16x16x32_bf16(al[mf], bh[n3], acc[mf][n3], 0, 0, 0);
            }
    }

    // Epilogue: D frag (col = l&15, row = 4*(l>>4)+r), add bias, route to Q/KV.
    #pragma unroll
    for (int n3 = 0; n3 < 3; ++n3) {
        int n0 = (wid * 3 + n3) * 16;
        float bb = bcat[n0 + lrow];
        float* base;
        size_t stride;
        if (n0 < 128)       { base = Q  + n0 + lrow;               stride = 128; }
        else if (n0 < 256)  { base = KV + (n0 - 128) + lrow;       stride = 256; }
        else                { base = KV + 128 + (n0 - 256) + lrow; stride = 256; }
        #pragma unroll
        for (int mf = 0; mf < 4; ++mf)
            #pragma unroll
            for (int r = 0; r < 4; ++r) {
                int grow = r0 + mf * 16 + ((l >> 4) << 2) + r;
                if (grow < N)
                    base[(size_t)grow * stride] = acc[mf][n3][r] + bb;
            }
    }
}

// ---------------- K2: rank pass (single atomic pass) ----------------
// U must be zeroed. Afterwards U[n] = degree(n), rank[e] = stable slot.
__global__ __launch_bounds__(256) void rank_kernel(
    const int* __restrict__ dst, int* __restrict__ U,
    int* __restrict__ rank, int E)
{
    int e = blockIdx.x * 256 + threadIdx.x;
    if (e < E) {
        int r = atomicAdd(&U[dst[e]], 1);
        __builtin_nontemporal_store(r, &rank[e]);
    }
}

// ---------------- K3a: per-tile (1024 counts) sums ----------------
__global__ __launch_bounds__(256) void scan_a(
    const int* __restrict__ C, int* __restrict__ tileSum, int N)
{
    __shared__ int red[256];
    const int t = blockIdx.x, tid = threadIdx.x;
    int base = t * 1024 + tid * 4;
    int s = 0;
    #pragma unroll
    for (int i = 0; i < 4; ++i)
        if (base + i < N) s += C[base + i];
    red[tid] = s;
    __syncthreads();
    for (int off = 128; off > 0; off >>= 1) {
        if (tid < off) red[tid] += red[tid + off];
        __syncthreads();
    }
    if (tid == 0) tileSum[t] = red[0];
}

// ---------------- K3b: exclusive scan of tile sums (single block) ----------------
__global__ __launch_bounds__(1024) void scan_b(
    const int* __restrict__ tileSum, int* __restrict__ tileOff, int numTiles)
{
    __shared__ int buf[1024];
    const int t = threadIdx.x;
    int v = (t < numTiles) ? tileSum[t] : 0;
    buf[t] = v;
    __syncthreads();
    for (int off = 1; off < 1024; off <<= 1) {
        int x = (t >= off) ? buf[t - off] : 0;
        __syncthreads();
        buf[t] += x;
        __syncthreads();
    }
    if (t < numTiles) tileOff[t] = buf[t] - v;  // exclusive
}

// ---------------- K3c: per-tile exclusive scan -> row offsets O ----------------
__global__ __launch_bounds__(256) void scan_c(
    const int* __restrict__ C, const int* __restrict__ tileOff,
    int* __restrict__ O, int N, int E)
{
    __shared__ int buf[256];
    const int t = blockIdx.x, tid = threadIdx.x;
    int base = t * 1024 + tid * 4;
    int c[4];
    #pragma unroll
    for (int i = 0; i < 4; ++i)
        c[i] = (base + i < N) ? C[base + i] : 0;
    int tsum = c[0] + c[1] + c[2] + c[3];
    buf[tid] = tsum;
    __syncthreads();
    for (int off = 1; off < 256; off <<= 1) {
        int x = (tid >= off) ? buf[tid - off] : 0;
        __syncthreads();
        buf[tid] += x;
        __syncthreads();
    }
    int run = buf[tid] - tsum + tileOff[t];  // exclusive prefix
    #pragma unroll
    for (int i = 0; i < 4; ++i) {
        if (base + i < N) O[base + i] = run;
        run += c[i];
    }
    if (t == 0 && tid == 0) O[N] = E;
}

// ---------------- K4: deterministic scatter (no atomics) ----------------
__global__ __launch_bounds__(256) void scatter_kernel(
    const int* __restrict__ src, const int* __restrict__ dst,
    const int* __restrict__ O, const int* __restrict__ rank,
    int* __restrict__ srclist, int E)
{
    int e = blockIdx.x * 256 + threadIdx.x;
    if (e < E) {
        __builtin_nontemporal_store(src[e], &srclist[O[dst[e]] + rank[e]]);
    }
}

// ---------------- K5: per-node aggregation (1 wave = 1 node) ----------------
// Half-wave-per-edge layout: lane l owns elements 4*(l&31)..+3 (float4).
// Lanes 0-31 process even edges of a pair-step, lanes 32-63 the odd edges.
// KV packed: node row = 256 floats (K then V) -> one contiguous 1KB region/edge.
__global__ __launch_bounds__(256) void agg_kernel(
    const float* __restrict__ Q, const float* __restrict__ KV,
    const int* __restrict__ O, const int* __restrict__ srclist,
    float* __restrict__ out, int N)
{
    const int l = threadIdx.x & 63;
    const int n = blockIdx.x * 4 + (threadIdx.x >> 6);
    if (n >= N) return;

    const int half = l >> 5;          // 0: even edge, 1: odd edge
    const int c4 = (l & 31) * 4;      // element offset within the row

    f4v q = __builtin_nontemporal_load((const f4v*)(Q + (size_t)n * HD + c4));
    f4v acc = {0.f, 0.f, 0.f, 0.f};
    float z = 0.f;
    const int start = __builtin_nontemporal_load(&O[n]);
    const int end   = __builtin_nontemporal_load(&O[n + 1]);

    for (int base = start; base < end; base += 64) {
        int sv = 0;
        if (base + l < end) sv = __builtin_nontemporal_load(&srclist[base + l]);
        const int cnt = min(64, end - base);
        int j = 0;
        for (; j + 8 <= cnt; j += 8) {          // 8 edges per iteration
            f4v kv[4], vv[4];
            #pragma unroll
            for (int u = 0; u < 4; ++u) {
                int s = __shfl(sv, j + 2 * u + half);
                const float* row = KV + (size_t)s * 256;
                kv[u] = *(const f4v*)(row + c4);
                vv[u] = *(const f4v*)(row + 128 + c4);
            }
            #pragma unroll
            for (int u = 0; u < 4; ++u) {
                float p = fmaf(kv[u][0], q[0],
                          fmaf(kv[u][1], q[1],
                          fmaf(kv[u][2], q[2], kv[u][3] * q[3])));
                p += __shfl_xor(p, 1);
                p += __shfl_xor(p, 2);
                float sc = __expf(fminf(5.f, fmaxf(-5.f, p * 0.25f)));
                z += sc;
                acc += sc * vv[u];
            }
        }
        for (; j < cnt; j += 2) {               // pair tail (maybe odd edge)
            int e = j + half;
            bool valid = e < cnt;
            int s = __shfl(sv, valid ? e : j);
            const float* row = KV + (size_t)s * 256;
            f4v kv = *(const f4v*)(row + c4);
            f4v vv = *(const f4v*)(row + 128 + c4);
            float p = fmaf(kv[0], q[0],
                      fmaf(kv[1], q[1],
                      fmaf(kv[2], q[2], kv[3] * q[3])));
            p += __shfl_xor(p, 1);
            p += __shfl_xor(p, 2);
            float sc = __expf(fminf(5.f, fmaxf(-5.f, p * 0.25f)));
            if (!valid) sc = 0.f;
            z += sc;
            acc += sc * vv;
        }
    }

    // Combine the two half-wave partial sums (same elements, disjoint edges).
    acc[0] += __shfl_xor(acc[0], 32);
    acc[1] += __shfl_xor(acc[1], 32);
    acc[2] += __shfl_xor(acc[2], 32);
    acc[3] += __shfl_xor(acc[3], 32);
    z      += __shfl_xor(z, 32);

    if (half == 0) {
        f4v res = acc / z;
        __builtin_nontemporal_store(res, (f4v*)(out + (size_t)n * HD + c4));
    }
}

extern "C" void kernel_launch(void* const* d_in, const int* in_sizes, int n_in,
                              void* d_out, int out_size, void* d_ws, size_t ws_size,
                              hipStream_t stream)
{
    const float* h  = (const float*)d_in[0];
    const float* WQ = (const float*)d_in[1];
    const float* bQ = (const float*)d_in[2];
    const float* WK = (const float*)d_in[3];
    const float* bK = (const float*)d_in[4];
    const float* WV = (const float*)d_in[5];
    const float* bV = (const float*)d_in[6];
    const int* src  = (const int*)d_in[7];
    const int* dst  = (const int*)d_in[8];
    float* out = (float*)d_out;

    const int N = in_sizes[0] / 128;
    const int E = in_sizes[7];
    const int numTiles = (N + 1023) / 1024;

    // Carve workspace (256B aligned chunks).
    char* w = (char*)d_ws;
    auto alloc = [&](size_t bytes) {
        char* p = w;
        w += (bytes + 255) & ~(size_t)255;
        return p;
    };
    float* Q  = (float*)alloc((size_t)N * HD * 4);
    float* KV = (float*)alloc((size_t)N * 256 * 4);
    int* O        = (int*)alloc((size_t)(N + 1) * 4);
    int* U        = (int*)alloc((size_t)N * 4);
    int* rank     = (int*)alloc((size_t)E * 4);
    int* tileSum  = (int*)alloc((size_t)numTiles * 4);
    int* tileOff  = (int*)alloc((size_t)numTiles * 4);
    int* srclist  = (int*)alloc((size_t)E * 4);
    unsigned short* Whi = (unsigned short*)alloc((size_t)96 * 512 * 2);
    unsigned short* Wlo = (unsigned short*)alloc((size_t)96 * 512 * 2);
    float* bcat   = (float*)alloc(384 * 4);

    hipMemsetAsync(U, 0, (size_t)N * 4, stream);

    prep_kernel<<<97, 256, 0, stream>>>(WQ, WK, WV, bQ, bK, bV, Whi, Wlo, bcat);
    qkv_kernel<<<(N + 63) / 64, 512, 0, stream>>>(h, Whi, Wlo, bcat, Q, KV, N);
    rank_kernel<<<(E + 255) / 256, 256, 0, stream>>>(dst, U, rank, E);
    scan_a<<<numTiles, 256, 0, stream>>>(U, tileSum, N);
    scan_b<<<1, 1024, 0, stream>>>(tileSum, tileOff, numTiles);
    scan_c<<<numTiles, 256, 0, stream>>>(U, tileOff, O, N, E);
    scatter_kernel<<<(E + 255) / 256, 256, 0, stream>>>(src, dst, O, rank, srclist, E);
    agg_kernel<<<(N + 3) / 4, 256, 0, stream>>>(Q, KV, O, srclist, out, N);
}

// Round 8
// 410.900 us; speedup vs baseline: 1.6424x; 1.2742x over previous
//
#include <hip/hip_runtime.h>

// Problem constants (from reference): IN_DIM=128, H=8, D=16, HD=128.
#define HD 128

typedef float f4v __attribute__((ext_vector_type(4)));
typedef float f32x4 __attribute__((ext_vector_type(4)));
typedef short short8 __attribute__((ext_vector_type(8)));      // 8 bf16 = 4 VGPRs
typedef _Float16 h8 __attribute__((ext_vector_type(8)));       // 8 fp16 = 16 B

// Round-to-nearest-even fp32 -> bf16 split: f ~= hi + lo (each bf16).
__device__ inline void bf16split(float f, unsigned short& hi, unsigned short& lo) {
    unsigned u = __builtin_bit_cast(unsigned, f);
    unsigned short h = (unsigned short)((u + 0x7FFFu + ((u >> 16) & 1u)) >> 16);
    float fh = __builtin_bit_cast(float, (unsigned)h << 16);
    float r = f - fh;                       // exact
    unsigned v = __builtin_bit_cast(unsigned, r);
    unsigned short l = (unsigned short)((v + 0x7FFFu + ((v >> 16) & 1u)) >> 16);
    hi = h; lo = l;
}

// ---------------- K0: weight prep ----------------
// Splits W_cat[128][384] (Q|K|V cols) into bf16 hi/lo in MFMA-fragment-ready
// layout: block (kt,nf) -> 512 entries, entry idx = l*8+e holds
// W[kt*32 + 8*(l>>4) + e][nf*16 + (l&15)].  Also builds bcat[384].
__global__ __launch_bounds__(256) void prep_kernel(
    const float* __restrict__ WQ, const float* __restrict__ WK,
    const float* __restrict__ WV,
    const float* __restrict__ bQ, const float* __restrict__ bK,
    const float* __restrict__ bV,
    unsigned short* __restrict__ Whi, unsigned short* __restrict__ Wlo,
    float* __restrict__ bcat)
{
    const int blk = blockIdx.x, tid = threadIdx.x;
    if (blk == 96) {
        for (int j = tid; j < 384; j += 256) {
            const float* b = (j < 128) ? bQ : (j < 256) ? bK : bV;
            bcat[j] = b[j & 127];
        }
        return;
    }
    const int kt = blk / 24, nf = blk % 24;
    #pragma unroll
    for (int t = 0; t < 2; ++t) {
        int idx = t * 256 + tid;           // 0..511
        int l = idx >> 3, e = idx & 7;
        int k = kt * 32 + ((l >> 4) << 3) + e;
        int j = nf * 16 + (l & 15);
        const float* W = (j < 128) ? WQ : (j < 256) ? WK : WV;
        float f = W[(size_t)k * 128 + (j & 127)];
        unsigned short hi, lo;
        bf16split(f, hi, lo);
        Whi[(size_t)blk * 512 + idx] = hi;
        Wlo[(size_t)blk * 512 + idx] = lo;
    }
}

// ---------------- K1: QKV projection via bf16x3 split MFMA ----------------
// Block: 512 threads (8 waves), 64 rows. Wave w computes rows 0..63 x cols
// [w*48, w*48+48). fp32 ~= hi*hi + hi*lo + lo*hi (lo*lo ~ 2^-17, dropped).
// Q -> [N,128] fp32.  K,V -> KV fp16, per-node row of 256 halfs (512 B):
// K elem j at (j>>2)*8 + (j&3), V elem j at (j>>2)*8 + 4 + (j&3)
// (groups of 4 K-halfs and 4 V-halfs interleaved -> one 16B load covers both).
__global__ __launch_bounds__(512, 2) void qkv_kernel(
    const float* __restrict__ h,
    const unsigned short* __restrict__ Whi, const unsigned short* __restrict__ Wlo,
    const float* __restrict__ bcat,
    float* __restrict__ Q, _Float16* __restrict__ KV, int N)
{
    __shared__ unsigned short hsh[64 * 136];   // +8 pad: 2-way max bank conflict
    __shared__ unsigned short hsl[64 * 136];
    const int tid = threadIdx.x;
    const int r0 = blockIdx.x * 64;

    // Stage h tile [64][128] as bf16 hi/lo (coalesced float4 loads).
    #pragma unroll
    for (int jj = 0; jj < 4; ++jj) {
        int idf4 = jj * 512 + tid;         // float4 index in tile
        int row = idf4 >> 5;
        int c4 = (idf4 & 31) << 2;
        f4v v = {0.f, 0.f, 0.f, 0.f};
        if (r0 + row < N)
            v = __builtin_nontemporal_load((const f4v*)(h + (size_t)(r0 + row) * 128 + c4));
        ushort4 hv, lv;
        bf16split(v[0], hv.x, lv.x);
        bf16split(v[1], hv.y, lv.y);
        bf16split(v[2], hv.z, lv.z);
        bf16split(v[3], hv.w, lv.w);
        *(ushort4*)&hsh[row * 136 + c4] = hv;
        *(ushort4*)&hsl[row * 136 + c4] = lv;
    }
    __syncthreads();

    const int wid = tid >> 6, l = tid & 63;
    const int lrow = l & 15;
    const int lkOff = (l >> 4) << 3;       // 0,8,16,24

    f32x4 acc[4][3];
    #pragma unroll
    for (int mf = 0; mf < 4; ++mf)
        #pragma unroll
        for (int n3 = 0; n3 < 3; ++n3)
            acc[mf][n3] = (f32x4){0.f, 0.f, 0.f, 0.f};

    #pragma unroll
    for (int kt = 0; kt < 4; ++kt) {
        short8 ah[4], al[4];
        #pragma unroll
        for (int mf = 0; mf < 4; ++mf) {
            int off = (mf * 16 + lrow) * 136 + kt * 32 + lkOff;
            ah[mf] = *(const short8*)&hsh[off];
            al[mf] = *(const short8*)&hsl[off];
        }
        short8 bh[3], bl[3];
        #pragma unroll
        for (int n3 = 0; n3 < 3; ++n3) {
            size_t fb = ((size_t)(kt * 24 + wid * 3 + n3)) * 512 + l * 8;
            bh[n3] = *(const short8*)&Whi[fb];
            bl[n3] = *(const short8*)&Wlo[fb];
        }
        #pragma unroll
        for (int mf = 0; mf < 4; ++mf)
            #pragma unroll
            for (int n3 = 0; n3 < 3; ++n3) {
                acc[mf][n3] = __builtin_amdgcn_mfma_f32_16x16x32_bf16(ah[mf], bh[n3], acc[mf][n3], 0, 0, 0);
                acc[mf][n3] = __builtin_amdgcn_mfma_f32_16x16x32_bf16(ah[mf], bl[n3], acc[mf][n3], 0, 0, 0);
                acc[mf][n3] = __builtin_amdgcn_mfma_f32_16x16x32_bf16(al[mf], bh[n3], acc[mf][n3], 0, 0, 0);
            }
    }

    // Epilogue: D frag (col = l&15, row = 4*(l>>4)+r), add bias, route outputs.
    #pragma unroll
    for (int n3 = 0; n3 < 3; ++n3) {
        int n0 = (wid * 3 + n3) * 16;
        int col = n0 + lrow;               // 0..383
        float bb = bcat[col];
        #pragma unroll
        for (int mf = 0; mf < 4; ++mf)
            #pragma unroll
            for (int r = 0; r < 4; ++r) {
                int grow = r0 + mf * 16 + ((l >> 4) << 2) + r;
                if (grow >= N) continue;
                float val = acc[mf][n3][r] + bb;
                if (col < 128) {
                    Q[(size_t)grow * HD + col] = val;
                } else if (col < 256) {
                    int j = col - 128;     // K element
                    KV[(size_t)grow * 256 + ((j >> 2) << 3) + (j & 3)] = (_Float16)val;
                } else {
                    int j = col - 256;     // V element
                    KV[(size_t)grow * 256 + ((j >> 2) << 3) + 4 + (j & 3)] = (_Float16)val;
                }
            }
    }
}

// ---------------- K2: rank pass (single atomic pass) ----------------
// U must be zeroed. Afterwards U[n] = degree(n), rank[e] = stable slot.
__global__ __launch_bounds__(256) void rank_kernel(
    const int* __restrict__ dst, int* __restrict__ U,
    int* __restrict__ rank, int E)
{
    int e = blockIdx.x * 256 + threadIdx.x;
    if (e < E) {
        int r = atomicAdd(&U[dst[e]], 1);
        __builtin_nontemporal_store(r, &rank[e]);
    }
}

// ---------------- K3a: per-tile (1024 counts) sums ----------------
__global__ __launch_bounds__(256) void scan_a(
    const int* __restrict__ C, int* __restrict__ tileSum, int N)
{
    __shared__ int red[256];
    const int t = blockIdx.x, tid = threadIdx.x;
    int base = t * 1024 + tid * 4;
    int s = 0;
    #pragma unroll
    for (int i = 0; i < 4; ++i)
        if (base + i < N) s += C[base + i];
    red[tid] = s;
    __syncthreads();
    for (int off = 128; off > 0; off >>= 1) {
        if (tid < off) red[tid] += red[tid + off];
        __syncthreads();
    }
    if (tid == 0) tileSum[t] = red[0];
}

// ---------------- K3b: exclusive scan of tile sums (single block) ----------------
__global__ __launch_bounds__(1024) void scan_b(
    const int* __restrict__ tileSum, int* __restrict__ tileOff, int numTiles)
{
    __shared__ int buf[1024];
    const int t = threadIdx.x;
    int v = (t < numTiles) ? tileSum[t] : 0;
    buf[t] = v;
    __syncthreads();
    for (int off = 1; off < 1024; off <<= 1) {
        int x = (t >= off) ? buf[t - off] : 0;
        __syncthreads();
        buf[t] += x;
        __syncthreads();
    }
    if (t < numTiles) tileOff[t] = buf[t] - v;  // exclusive
}

// ---------------- K3c: per-tile exclusive scan -> row offsets O ----------------
__global__ __launch_bounds__(256) void scan_c(
    const int* __restrict__ C, const int* __restrict__ tileOff,
    int* __restrict__ O, int N, int E)
{
    __shared__ int buf[256];
    const int t = blockIdx.x, tid = threadIdx.x;
    int base = t * 1024 + tid * 4;
    int c[4];
    #pragma unroll
    for (int i = 0; i < 4; ++i)
        c[i] = (base + i < N) ? C[base + i] : 0;
    int tsum = c[0] + c[1] + c[2] + c[3];
    buf[tid] = tsum;
    __syncthreads();
    for (int off = 1; off < 256; off <<= 1) {
        int x = (tid >= off) ? buf[tid - off] : 0;
        __syncthreads();
        buf[tid] += x;
        __syncthreads();
    }
    int run = buf[tid] - tsum + tileOff[t];  // exclusive prefix
    #pragma unroll
    for (int i = 0; i < 4; ++i) {
        if (base + i < N) O[base + i] = run;
        run += c[i];
    }
    if (t == 0 && tid == 0) O[N] = E;
}

// ---------------- K4: deterministic scatter (no atomics) ----------------
__global__ __launch_bounds__(256) void scatter_kernel(
    const int* __restrict__ src, const int* __restrict__ dst,
    const int* __restrict__ O, const int* __restrict__ rank,
    int* __restrict__ srclist, int E)
{
    int e = blockIdx.x * 256 + threadIdx.x;
    if (e < E) {
        __builtin_nontemporal_store(src[e], &srclist[O[dst[e]] + rank[e]]);
    }
}

// ---------------- K5: per-node aggregation (1 wave = 1 node) ----------------
// Half-wave-per-edge: chunk c = l&31 owns elements 4c..4c+3 of K and V.
// KV fp16 row (512 B): one 16 B load at row + c*8 gives [K 4c..+3 | V 4c..+3].
// Lanes 0-31 process even edges of a pair-step, lanes 32-63 odd edges.
__global__ __launch_bounds__(256) void agg_kernel(
    const float* __restrict__ Q, const _Float16* __restrict__ KV,
    const int* __restrict__ O, const int* __restrict__ srclist,
    float* __restrict__ out, int N)
{
    const int l = threadIdx.x & 63;
    const int n = blockIdx.x * 4 + (threadIdx.x >> 6);
    if (n >= N) return;

    const int half = l >> 5;          // 0: even edge, 1: odd edge
    const int c = l & 31;             // chunk index
    const int c4 = c * 4;             // element offset within the 128-row

    f4v q = __builtin_nontemporal_load((const f4v*)(Q + (size_t)n * HD + c4));
    f4v acc = {0.f, 0.f, 0.f, 0.f};
    float z = 0.f;
    const int start = __builtin_nontemporal_load(&O[n]);
    const int end   = __builtin_nontemporal_load(&O[n + 1]);

    for (int base = start; base < end; base += 64) {
        int sv = 0;
        if (base + l < end) sv = __builtin_nontemporal_load(&srclist[base + l]);
        const int cnt = min(64, end - base);
        int j = 0;
        for (; j + 16 <= cnt; j += 16) {        // 16 edges: 8 loads in flight/lane
            h8 kv[8];
            #pragma unroll
            for (int u = 0; u < 8; ++u) {
                int s = __shfl(sv, j + 2 * u + half);
                kv[u] = *(const h8*)(KV + (size_t)s * 256 + c * 8);
            }
            #pragma unroll
            for (int u = 0; u < 8; ++u) {
                float p = fmaf((float)kv[u][0], q[0],
                          fmaf((float)kv[u][1], q[1],
                          fmaf((float)kv[u][2], q[2], (float)kv[u][3] * q[3])));
                p += __shfl_xor(p, 1);
                p += __shfl_xor(p, 2);
                float sc = __expf(fminf(5.f, fmaxf(-5.f, p * 0.25f)));
                z += sc;
                acc[0] = fmaf(sc, (float)kv[u][4], acc[0]);
                acc[1] = fmaf(sc, (float)kv[u][5], acc[1]);
                acc[2] = fmaf(sc, (float)kv[u][6], acc[2]);
                acc[3] = fmaf(sc, (float)kv[u][7], acc[3]);
            }
        }
        for (; j + 8 <= cnt; j += 8) {          // 8 edges
            h8 kv[4];
            #pragma unroll
            for (int u = 0; u < 4; ++u) {
                int s = __shfl(sv, j + 2 * u + half);
                kv[u] = *(const h8*)(KV + (size_t)s * 256 + c * 8);
            }
            #pragma unroll
            for (int u = 0; u < 4; ++u) {
                float p = fmaf((float)kv[u][0], q[0],
                          fmaf((float)kv[u][1], q[1],
                          fmaf((float)kv[u][2], q[2], (float)kv[u][3] * q[3])));
                p += __shfl_xor(p, 1);
                p += __shfl_xor(p, 2);
                float sc = __expf(fminf(5.f, fmaxf(-5.f, p * 0.25f)));
                z += sc;
                acc[0] = fmaf(sc, (float)kv[u][4], acc[0]);
                acc[1] = fmaf(sc, (float)kv[u][5], acc[1]);
                acc[2] = fmaf(sc, (float)kv[u][6], acc[2]);
                acc[3] = fmaf(sc, (float)kv[u][7], acc[3]);
            }
        }
        for (; j < cnt; j += 2) {               // pair tail (maybe odd edge)
            int e = j + half;
            bool valid = e < cnt;
            int s = __shfl(sv, valid ? e : j);
            h8 kv = *(const h8*)(KV + (size_t)s * 256 + c * 8);
            float p = fmaf((float)kv[0], q[0],
                      fmaf((float)kv[1], q[1],
                      fmaf((float)kv[2], q[2], (float)kv[3] * q[3])));
            p += __shfl_xor(p, 1);
            p += __shfl_xor(p, 2);
            float sc = __expf(fminf(5.f, fmaxf(-5.f, p * 0.25f)));
            if (!valid) sc = 0.f;
            z += sc;
            acc[0] = fmaf(sc, (float)kv[4], acc[0]);
            acc[1] = fmaf(sc, (float)kv[5], acc[1]);
            acc[2] = fmaf(sc, (float)kv[6], acc[2]);
            acc[3] = fmaf(sc, (float)kv[7], acc[3]);
        }
    }

    // Combine the two half-wave partial sums (same elements, disjoint edges).
    acc[0] += __shfl_xor(acc[0], 32);
    acc[1] += __shfl_xor(acc[1], 32);
    acc[2] += __shfl_xor(acc[2], 32);
    acc[3] += __shfl_xor(acc[3], 32);
    z      += __shfl_xor(z, 32);

    if (half == 0) {
        f4v res = acc / z;
        __builtin_nontemporal_store(res, (f4v*)(out + (size_t)n * HD + c4));
    }
}

extern "C" void kernel_launch(void* const* d_in, const int* in_sizes, int n_in,
                              void* d_out, int out_size, void* d_ws, size_t ws_size,
                              hipStream_t stream)
{
    const float* h  = (const float*)d_in[0];
    const float* WQ = (const float*)d_in[1];
    const float* bQ = (const float*)d_in[2];
    const float* WK = (const float*)d_in[3];
    const float* bK = (const float*)d_in[4];
    const float* WV = (const float*)d_in[5];
    const float* bV = (const float*)d_in[6];
    const int* src  = (const int*)d_in[7];
    const int* dst  = (const int*)d_in[8];
    float* out = (float*)d_out;

    const int N = in_sizes[0] / 128;
    const int E = in_sizes[7];
    const int numTiles = (N + 1023) / 1024;

    // Carve workspace (256B aligned chunks).
    char* w = (char*)d_ws;
    auto alloc = [&](size_t bytes) {
        char* p = w;
        w += (bytes + 255) & ~(size_t)255;
        return p;
    };
    float* Q      = (float*)alloc((size_t)N * HD * 4);
    _Float16* KV  = (_Float16*)alloc((size_t)N * 256 * 2);
    int* O        = (int*)alloc((size_t)(N + 1) * 4);
    int* U        = (int*)alloc((size_t)N * 4);
    int* rank     = (int*)alloc((size_t)E * 4);
    int* tileSum  = (int*)alloc((size_t)numTiles * 4);
    int* tileOff  = (int*)alloc((size_t)numTiles * 4);
    int* srclist  = (int*)alloc((size_t)E * 4);
    unsigned short* Whi = (unsigned short*)alloc((size_t)96 * 512 * 2);
    unsigned short* Wlo = (unsigned short*)alloc((size_t)96 * 512 * 2);
    float* bcat   = (float*)alloc(384 * 4);

    hipMemsetAsync(U, 0, (size_t)N * 4, stream);

    prep_kernel<<<97, 256, 0, stream>>>(WQ, WK, WV, bQ, bK, bV, Whi, Wlo, bcat);
    qkv_kernel<<<(N + 63) / 64, 512, 0, stream>>>(h, Whi, Wlo, bcat, Q, KV, N);
    rank_kernel<<<(E + 255) / 256, 256, 0, stream>>>(dst, U, rank, E);
    scan_a<<<numTiles, 256, 0, stream>>>(U, tileSum, N);
    scan_b<<<1, 1024, 0, stream>>>(tileSum, tileOff, numTiles);
    scan_c<<<numTiles, 256, 0, stream>>>(U, tileOff, O, N, E);
    scatter_kernel<<<(E + 255) / 256, 256, 0, stream>>>(src, dst, O, rank, srclist, E);
    agg_kernel<<<(N + 3) / 4, 256, 0, stream>>>(Q, KV, O, srclist, out, N);
}

// Round 10
// 333.119 us; speedup vs baseline: 2.0259x; 1.2335x over previous
//
#include <hip/hip_runtime.h>

// Problem constants (from reference): IN_DIM=128, H=8, D=16, HD=128.
#define HD 128

typedef float f4v __attribute__((ext_vector_type(4)));
typedef float f32x4 __attribute__((ext_vector_type(4)));
typedef short short8 __attribute__((ext_vector_type(8)));      // 8 bf16 = 4 VGPRs
typedef _Float16 h8 __attribute__((ext_vector_type(8)));       // 8 fp16 = 16 B

// Round-to-nearest-even fp32 -> bf16 split: f ~= hi + lo (each bf16).
__device__ inline void bf16split(float f, unsigned short& hi, unsigned short& lo) {
    unsigned u = __builtin_bit_cast(unsigned, f);
    unsigned short h = (unsigned short)((u + 0x7FFFu + ((u >> 16) & 1u)) >> 16);
    float fh = __builtin_bit_cast(float, (unsigned)h << 16);
    float r = f - fh;                       // exact
    unsigned v = __builtin_bit_cast(unsigned, r);
    unsigned short l = (unsigned short)((v + 0x7FFFu + ((v >> 16) & 1u)) >> 16);
    hi = h; lo = l;
}

// ---------------- K0: weight prep ----------------
__global__ __launch_bounds__(256) void prep_kernel(
    const float* __restrict__ WQ, const float* __restrict__ WK,
    const float* __restrict__ WV,
    const float* __restrict__ bQ, const float* __restrict__ bK,
    const float* __restrict__ bV,
    unsigned short* __restrict__ Whi, unsigned short* __restrict__ Wlo,
    float* __restrict__ bcat)
{
    const int blk = blockIdx.x, tid = threadIdx.x;
    if (blk == 96) {
        for (int j = tid; j < 384; j += 256) {
            const float* b = (j < 128) ? bQ : (j < 256) ? bK : bV;
            bcat[j] = b[j & 127];
        }
        return;
    }
    const int kt = blk / 24, nf = blk % 24;
    #pragma unroll
    for (int t = 0; t < 2; ++t) {
        int idx = t * 256 + tid;           // 0..511
        int l = idx >> 3, e = idx & 7;
        int k = kt * 32 + ((l >> 4) << 3) + e;
        int j = nf * 16 + (l & 15);
        const float* W = (j < 128) ? WQ : (j < 256) ? WK : WV;
        float f = W[(size_t)k * 128 + (j & 127)];
        unsigned short hi, lo;
        bf16split(f, hi, lo);
        Whi[(size_t)blk * 512 + idx] = hi;
        Wlo[(size_t)blk * 512 + idx] = lo;
    }
}

// ---------------- K1: QKV projection via bf16x3 split MFMA ----------------
__global__ __launch_bounds__(512, 2) void qkv_kernel(
    const float* __restrict__ h,
    const unsigned short* __restrict__ Whi, const unsigned short* __restrict__ Wlo,
    const float* __restrict__ bcat,
    float* __restrict__ Q, _Float16* __restrict__ KV, int N)
{
    __shared__ unsigned short hsh[64 * 136];   // +8 pad: 2-way max bank conflict
    __shared__ unsigned short hsl[64 * 136];
    const int tid = threadIdx.x;
    const int r0 = blockIdx.x * 64;

    #pragma unroll
    for (int jj = 0; jj < 4; ++jj) {
        int idf4 = jj * 512 + tid;         // float4 index in tile
        int row = idf4 >> 5;
        int c4 = (idf4 & 31) << 2;
        f4v v = {0.f, 0.f, 0.f, 0.f};
        if (r0 + row < N)
            v = __builtin_nontemporal_load((const f4v*)(h + (size_t)(r0 + row) * 128 + c4));
        ushort4 hv, lv;
        bf16split(v[0], hv.x, lv.x);
        bf16split(v[1], hv.y, lv.y);
        bf16split(v[2], hv.z, lv.z);
        bf16split(v[3], hv.w, lv.w);
        *(ushort4*)&hsh[row * 136 + c4] = hv;
        *(ushort4*)&hsl[row * 136 + c4] = lv;
    }
    __syncthreads();

    const int wid = tid >> 6, l = tid & 63;
    const int lrow = l & 15;
    const int lkOff = (l >> 4) << 3;       // 0,8,16,24

    f32x4 acc[4][3];
    #pragma unroll
    for (int mf = 0; mf < 4; ++mf)
        #pragma unroll
        for (int n3 = 0; n3 < 3; ++n3)
            acc[mf][n3] = (f32x4){0.f, 0.f, 0.f, 0.f};

    #pragma unroll
    for (int kt = 0; kt < 4; ++kt) {
        short8 ah[4], al[4];
        #pragma unroll
        for (int mf = 0; mf < 4; ++mf) {
            int off = (mf * 16 + lrow) * 136 + kt * 32 + lkOff;
            ah[mf] = *(const short8*)&hsh[off];
            al[mf] = *(const short8*)&hsl[off];
        }
        short8 bh[3], bl[3];
        #pragma unroll
        for (int n3 = 0; n3 < 3; ++n3) {
            size_t fb = ((size_t)(kt * 24 + wid * 3 + n3)) * 512 + l * 8;
            bh[n3] = *(const short8*)&Whi[fb];
            bl[n3] = *(const short8*)&Wlo[fb];
        }
        #pragma unroll
        for (int mf = 0; mf < 4; ++mf)
            #pragma unroll
            for (int n3 = 0; n3 < 3; ++n3) {
                acc[mf][n3] = __builtin_amdgcn_mfma_f32_16x16x32_bf16(ah[mf], bh[n3], acc[mf][n3], 0, 0, 0);
                acc[mf][n3] = __builtin_amdgcn_mfma_f32_16x16x32_bf16(ah[mf], bl[n3], acc[mf][n3], 0, 0, 0);
                acc[mf][n3] = __builtin_amdgcn_mfma_f32_16x16x32_bf16(al[mf], bh[n3], acc[mf][n3], 0, 0, 0);
            }
    }

    #pragma unroll
    for (int n3 = 0; n3 < 3; ++n3) {
        int n0 = (wid * 3 + n3) * 16;
        int col = n0 + lrow;               // 0..383
        float bb = bcat[col];
        #pragma unroll
        for (int mf = 0; mf < 4; ++mf)
            #pragma unroll
            for (int r = 0; r < 4; ++r) {
                int grow = r0 + mf * 16 + ((l >> 4) << 2) + r;
                if (grow >= N) continue;
                float val = acc[mf][n3][r] + bb;
                if (col < 128) {
                    Q[(size_t)grow * HD + col] = val;
                } else if (col < 256) {
                    int j = col - 128;     // K element
                    KV[(size_t)grow * 256 + ((j >> 2) << 3) + (j & 3)] = (_Float16)val;
                } else {
                    int j = col - 256;     // V element
                    KV[(size_t)grow * 256 + ((j >> 2) << 3) + 4 + (j & 3)] = (_Float16)val;
                }
            }
    }
}

// ---------------- CSR build via 2-level counting sort (bucket = dst>>9) -----

// K2a: bucket histogram. bucketCnt must be zeroed.
__global__ __launch_bounds__(256) void bhist_kernel(
    const int* __restrict__ dst, int* __restrict__ bucketCnt, int E, int NBk)
{
    __shared__ int hst[512];
    for (int i = threadIdx.x; i < NBk; i += 256) hst[i] = 0;
    __syncthreads();
    for (int e = blockIdx.x * 256 + threadIdx.x; e < E; e += gridDim.x * 256)
        atomicAdd(&hst[dst[e] >> 9], 1);
    __syncthreads();
    for (int i = threadIdx.x; i < NBk; i += 256)
        if (hst[i]) atomicAdd(&bucketCnt[i], hst[i]);
}

// K2b: exclusive scan of bucketCnt (NBk <= 256) -> bucketBase[NBk+1], cursor.
__global__ __launch_bounds__(256) void bscan_kernel(
    const int* __restrict__ bucketCnt, int* __restrict__ bucketBase,
    int* __restrict__ bucketCursor, int NBk)
{
    __shared__ int sc[256];
    const int t = threadIdx.x;
    int v = (t < NBk) ? bucketCnt[t] : 0;
    sc[t] = v;
    __syncthreads();
    for (int off = 1; off < 256; off <<= 1) {
        int x = (t >= off) ? sc[t - off] : 0;
        __syncthreads();
        sc[t] += x;
        __syncthreads();
    }
    if (t < NBk) {
        int base = sc[t] - v;
        bucketBase[t] = base;
        bucketCursor[t] = base;
    }
    if (t == NBk - 1) bucketBase[NBk] = sc[t];
}

// K2c: grouped scatter of (src,dst) pairs into bucket regions of ebuf.
// Block: 1024 thr, 8192 edges. LDS-group by bucket, one global atomic/bucket.
#define SC_CHUNK 8192
__global__ __launch_bounds__(1024, 1) void bscatter_kernel(
    const int* __restrict__ src, const int* __restrict__ dst,
    int* __restrict__ bucketCursor, int2* __restrict__ ebuf, int E, int NBk)
{
    __shared__ int cnt[256], sc[256], lbase[256], lcur[256], gdst[256];
    __shared__ int2 buf[SC_CHUNK];
    __shared__ short bkt[SC_CHUNK];
    const int tid = threadIdx.x;
    const int e0 = blockIdx.x * SC_CHUNK;
    const int count = min(SC_CHUNK, E - e0);

    for (int i = tid; i < 256; i += 1024) cnt[i] = 0;
    __syncthreads();

    int d8[8], s8[8], b8[8];
    #pragma unroll
    for (int u = 0; u < 8; ++u) {
        int i = u * 1024 + tid;
        if (i < count) {
            d8[u] = dst[e0 + i];
            s8[u] = src[e0 + i];
            b8[u] = d8[u] >> 9;
            atomicAdd(&cnt[b8[u]], 1);
        }
    }
    __syncthreads();

    // exclusive scan of cnt over first 256 threads
    if (tid < 256) sc[tid] = cnt[tid];
    __syncthreads();
    for (int off = 1; off < 256; off <<= 1) {
        int x = (tid < 256 && tid >= off) ? sc[tid - off] : 0;
        __syncthreads();
        if (tid < 256) sc[tid] += x;
        __syncthreads();
    }
    if (tid < 256) {
        lbase[tid] = sc[tid] - cnt[tid];
        lcur[tid] = lbase[tid];
        if (tid < NBk && cnt[tid])
            gdst[tid] = atomicAdd(&bucketCursor[tid], cnt[tid]);
    }
    __syncthreads();

    #pragma unroll
    for (int u = 0; u < 8; ++u) {
        int i = u * 1024 + tid;
        if (i < count) {
            int p = atomicAdd(&lcur[b8[u]], 1);
            buf[p] = make_int2(s8[u], d8[u]);
            bkt[p] = (short)b8[u];
        }
    }
    __syncthreads();

    for (int i = tid; i < count; i += 1024) {
        int b = bkt[i];
        ebuf[gdst[b] + (i - lbase[b])] = buf[i];
    }
}

// K2d: per-bucket CSR finalize. One block per bucket (512 dst nodes).
// Builds O[] for its nodes and scatters src ids into its srclist window.
__global__ __launch_bounds__(1024, 1) void bcsr_kernel(
    const int2* __restrict__ ebuf, const int* __restrict__ bucketBase,
    int* __restrict__ O, int* __restrict__ srclist, int N, int E, int NBk)
{
    __shared__ int hst[512], sc[512], pre[512], cur[512];
    const int b = blockIdx.x, tid = threadIdx.x;
    const int nodes0 = b << 9;
    const int nn = min(512, N - nodes0);
    const int e0 = bucketBase[b], e1 = bucketBase[b + 1];
    const int cnt = e1 - e0;

    for (int i = tid; i < 512; i += 1024) hst[i] = 0;
    __syncthreads();
    for (int i = tid; i < cnt; i += 1024)
        atomicAdd(&hst[ebuf[e0 + i].y & 511], 1);
    __syncthreads();

    // exclusive scan over 512 (first 512 threads)
    if (tid < 512) sc[tid] = hst[tid];
    __syncthreads();
    for (int off = 1; off < 512; off <<= 1) {
        int x = (tid < 512 && tid >= off) ? sc[tid - off] : 0;
        __syncthreads();
        if (tid < 512) sc[tid] += x;
        __syncthreads();
    }
    if (tid < 512) {
        pre[tid] = sc[tid] - hst[tid];
        cur[tid] = pre[tid];
        if (tid < nn) O[nodes0 + tid] = e0 + pre[tid];
    }
    if (b == NBk - 1 && tid == 0) O[N] = E;
    __syncthreads();

    for (int i = tid; i < cnt; i += 1024) {
        int2 p = ebuf[e0 + i];
        int pos = atomicAdd(&cur[p.y & 511], 1);
        srclist[e0 + pos] = p.x;
    }
}

// ---------------- K5: per-node aggregation (1 wave = 1 node) ----------------
__global__ __launch_bounds__(256) void agg_kernel(
    const float* __restrict__ Q, const _Float16* __restrict__ KV,
    const int* __restrict__ O, const int* __restrict__ srclist,
    float* __restrict__ out, int N)
{
    const int l = threadIdx.x & 63;
    const int n = blockIdx.x * 4 + (threadIdx.x >> 6);
    if (n >= N) return;

    const int half = l >> 5;          // 0: even edge, 1: odd edge
    const int c = l & 31;             // chunk index
    const int c4 = c * 4;             // element offset within the 128-row

    f4v q = __builtin_nontemporal_load((const f4v*)(Q + (size_t)n * HD + c4));
    f4v acc = {0.f, 0.f, 0.f, 0.f};
    float z = 0.f;
    const int start = __builtin_nontemporal_load(&O[n]);
    const int end   = __builtin_nontemporal_load(&O[n + 1]);

    for (int base = start; base < end; base += 64) {
        int sv = 0;
        if (base + l < end) sv = __builtin_nontemporal_load(&srclist[base + l]);
        const int cnt = min(64, end - base);
        int j = 0;
        for (; j + 16 <= cnt; j += 16) {        // 16 edges: 8 loads in flight/lane
            h8 kv[8];
            #pragma unroll
            for (int u = 0; u < 8; ++u) {
                int s = __shfl(sv, j + 2 * u + half);
                kv[u] = *(const h8*)(KV + (size_t)s * 256 + c * 8);
            }
            #pragma unroll
            for (int u = 0; u < 8; ++u) {
                float p = fmaf((float)kv[u][0], q[0],
                          fmaf((float)kv[u][1], q[1],
                          fmaf((float)kv[u][2], q[2], (float)kv[u][3] * q[3])));
                p += __shfl_xor(p, 1);
                p += __shfl_xor(p, 2);
                float sc = __expf(fminf(5.f, fmaxf(-5.f, p * 0.25f)));
                z += sc;
                acc[0] = fmaf(sc, (float)kv[u][4], acc[0]);
                acc[1] = fmaf(sc, (float)kv[u][5], acc[1]);
                acc[2] = fmaf(sc, (float)kv[u][6], acc[2]);
                acc[3] = fmaf(sc, (float)kv[u][7], acc[3]);
            }
        }
        for (; j + 8 <= cnt; j += 8) {          // 8 edges
            h8 kv[4];
            #pragma unroll
            for (int u = 0; u < 4; ++u) {
                int s = __shfl(sv, j + 2 * u + half);
                kv[u] = *(const h8*)(KV + (size_t)s * 256 + c * 8);
            }
            #pragma unroll
            for (int u = 0; u < 4; ++u) {
                float p = fmaf((float)kv[u][0], q[0],
                          fmaf((float)kv[u][1], q[1],
                          fmaf((float)kv[u][2], q[2], (float)kv[u][3] * q[3])));
                p += __shfl_xor(p, 1);
                p += __shfl_xor(p, 2);
                float sc = __expf(fminf(5.f, fmaxf(-5.f, p * 0.25f)));
                z += sc;
                acc[0] = fmaf(sc, (float)kv[u][4], acc[0]);
                acc[1] = fmaf(sc, (float)kv[u][5], acc[1]);
                acc[2] = fmaf(sc, (float)kv[u][6], acc[2]);
                acc[3] = fmaf(sc, (float)kv[u][7], acc[3]);
            }
        }
        for (; j < cnt; j += 2) {               // pair tail (maybe odd edge)
            int e = j + half;
            bool valid = e < cnt;
            int s = __shfl(sv, valid ? e : j);
            h8 kv = *(const h8*)(KV + (size_t)s * 256 + c * 8);
            float p = fmaf((float)kv[0], q[0],
                      fmaf((float)kv[1], q[1],
                      fmaf((float)kv[2], q[2], (float)kv[3] * q[3])));
            p += __shfl_xor(p, 1);
            p += __shfl_xor(p, 2);
            float sc = __expf(fminf(5.f, fmaxf(-5.f, p * 0.25f)));
            if (!valid) sc = 0.f;
            z += sc;
            acc[0] = fmaf(sc, (float)kv[4], acc[0]);
            acc[1] = fmaf(sc, (float)kv[5], acc[1]);
            acc[2] = fmaf(sc, (float)kv[6], acc[2]);
            acc[3] = fmaf(sc, (float)kv[7], acc[3]);
        }
    }

    acc[0] += __shfl_xor(acc[0], 32);
    acc[1] += __shfl_xor(acc[1], 32);
    acc[2] += __shfl_xor(acc[2], 32);
    acc[3] += __shfl_xor(acc[3], 32);
    z      += __shfl_xor(z, 32);

    if (half == 0) {
        f4v res = acc / z;
        __builtin_nontemporal_store(res, (f4v*)(out + (size_t)n * HD + c4));
    }
}

extern "C" void kernel_launch(void* const* d_in, const int* in_sizes, int n_in,
                              void* d_out, int out_size, void* d_ws, size_t ws_size,
                              hipStream_t stream)
{
    const float* h  = (const float*)d_in[0];
    const float* WQ = (const float*)d_in[1];
    const float* bQ = (const float*)d_in[2];
    const float* WK = (const float*)d_in[3];
    const float* bK = (const float*)d_in[4];
    const float* WV = (const float*)d_in[5];
    const float* bV = (const float*)d_in[6];
    const int* src  = (const int*)d_in[7];
    const int* dst  = (const int*)d_in[8];
    float* out = (float*)d_out;

    const int N = in_sizes[0] / 128;
    const int E = in_sizes[7];
    const int NBk = (N + 511) >> 9;        // buckets of 512 nodes

    // Carve workspace (256B aligned chunks).
    char* w = (char*)d_ws;
    auto alloc = [&](size_t bytes) {
        char* p = w;
        w += (bytes + 255) & ~(size_t)255;
        return p;
    };
    float* Q      = (float*)alloc((size_t)N * HD * 4);
    _Float16* KV  = (_Float16*)alloc((size_t)N * 256 * 2);
    int* O        = (int*)alloc((size_t)(N + 1) * 4);
    int2* ebuf    = (int2*)alloc((size_t)E * 8);
    int* srclist  = (int*)alloc((size_t)E * 4);
    int* bucketCnt    = (int*)alloc((size_t)(NBk + 1) * 4);
    int* bucketBase   = (int*)alloc((size_t)(NBk + 1) * 4);
    int* bucketCursor = (int*)alloc((size_t)(NBk + 1) * 4);
    unsigned short* Whi = (unsigned short*)alloc((size_t)96 * 512 * 2);
    unsigned short* Wlo = (unsigned short*)alloc((size_t)96 * 512 * 2);
    float* bcat   = (float*)alloc(384 * 4);

    hipMemsetAsync(bucketCnt, 0, (size_t)(NBk + 1) * 4, stream);

    prep_kernel<<<97, 256, 0, stream>>>(WQ, WK, WV, bQ, bK, bV, Whi, Wlo, bcat);
    qkv_kernel<<<(N + 63) / 64, 512, 0, stream>>>(h, Whi, Wlo, bcat, Q, KV, N);
    bhist_kernel<<<512, 256, 0, stream>>>(dst, bucketCnt, E, NBk);
    bscan_kernel<<<1, 256, 0, stream>>>(bucketCnt, bucketBase, bucketCursor, NBk);
    bscatter_kernel<<<(E + SC_CHUNK - 1) / SC_CHUNK, 1024, 0, stream>>>(
        src, dst, bucketCursor, ebuf, E, NBk);
    bcsr_kernel<<<NBk, 1024, 0, stream>>>(ebuf, bucketBase, O, srclist, N, E, NBk);
    agg_kernel<<<(N + 3) / 4, 256, 0, stream>>>(Q, KV, O, srclist, out, N);
}